// Round 11
// baseline (60.205 us; speedup 1.0000x reference)
//
#include <hip/hip_runtime.h>
#include <hip/hip_bf16.h>

typedef short bf16x8 __attribute__((ext_vector_type(8)));
typedef float f32x4 __attribute__((ext_vector_type(4)));
typedef unsigned short u16;

#define B_    32
#define L_    8192
#define C_    8
#define P_    512
#define D_    256
#define SED_  16
#define CED_  8
#define INDIM 2576
#define NROWS (B_ * P_)

#define TB_WTS 0
#define TB_IWT 1
#define TB_SYS 2
#define TB_GW1 3
#define TB_BWB 4
#define TB_CH0 5
#define TB_W2G 10
#define TB_B2  11

__device__ __forceinline__ u16 f2bf(float f) {
    __hip_bfloat16 h = __float2bfloat16(f);
    return *reinterpret_cast<u16*>(&h);
}

// ================================================================= zero tabF
__global__ __launch_bounds__(256) void k_zero(float* __restrict__ tabF) {
    tabF[blockIdx.x * 256 + threadIdx.x] = 0.f;
}

// ================================================================= prep (r9/r10 version — verified)
__global__ __launch_bounds__(256) void k_prep(
    const float* __restrict__ W1, const float* __restrict__ W2,
    const float* __restrict__ g1, const float* __restrict__ bb1,
    const float* __restrict__ g2, const float* __restrict__ bb2,
    const float* __restrict__ ce, const float* __restrict__ se,
    const int* __restrict__ ctm, const int* __restrict__ sysid,
    u16* __restrict__ wdt, u16* __restrict__ w2t,
    float* __restrict__ tabF, float* __restrict__ scal)
{
    __shared__ __attribute__((aligned(16))) char sh[8320];
    int c = blockIdx.x, n = threadIdx.x;

    if (c < 81) {
        float* sg = (float*)sh;
        float* sb = sg + 32;
        float* st = sb + 32;
        float (*cs5)[32] = (float(*)[32])(st + 32);
        int sid = sysid[0];
        int k0 = c * 32;
        int kend = INDIM - k0; if (kend > 32) kend = 32;
        int type = (k0 < 256) ? 0 : (k0 < 512) ? 1 : (k0 < 2560) ? 2 : 3;
        if (n < kend) {
            int k = k0 + n;
            sg[n] = g1[k]; sb[n] = bb1[k];
            float xv = 0.f;
            if (type == 1) xv = (float)((k - 256) >> 2);
            if (type == 3) xv = se[sid * SED_ + (k - 2560)];
            st[n] = xv;
        }
        if (type == 2 && n < 160) {
            int s = n >> 5, kt = n & 31, k = k0 + kt;
            cs5[s][kt] = ce[ctm[sid * 20 + s + ((k >> 3) & 3)] * CED_ + (k & 7)];
        }
        __syncthreads();
        float pg = 0, pb = 0, ai = 0, as_ = 0;
        float a5 = 0, a6 = 0, a7 = 0, a8 = 0, a9 = 0;
#pragma unroll 8
        for (int kt = 0; kt < kend; ++kt) {
            float wv = W1[(size_t)(k0 + kt) * D_ + n];
            float gw = sg[kt] * wv;
            pg += gw; pb += sb[kt] * wv;
            if (type == 1) ai += st[kt] * gw;
            if (type == 2) {
                a5 += cs5[0][kt] * gw; a6 += cs5[1][kt] * gw; a7 += cs5[2][kt] * gw;
                a8 += cs5[3][kt] * gw; a9 += cs5[4][kt] * gw;
            }
            if (type == 3) as_ += st[kt] * gw;
        }
        atomicAdd(&tabF[TB_GW1 * 256 + n], pg);
        atomicAdd(&tabF[TB_BWB * 256 + n], pb);
        if (type == 1) {
            atomicAdd(&tabF[TB_WTS * 256 + n], pg);
            atomicAdd(&tabF[TB_IWT * 256 + n], ai);
        }
        if (type == 2) {
            atomicAdd(&tabF[(TB_CH0 + 0) * 256 + n], a5);
            atomicAdd(&tabF[(TB_CH0 + 1) * 256 + n], a6);
            atomicAdd(&tabF[(TB_CH0 + 2) * 256 + n], a7);
            atomicAdd(&tabF[(TB_CH0 + 3) * 256 + n], a8);
            atomicAdd(&tabF[(TB_CH0 + 4) * 256 + n], a9);
        }
        if (type == 3) atomicAdd(&tabF[TB_SYS * 256 + n], as_);
    } else if (c < 89) {
        float* sg = (float*)sh;
        float* sb = sg + 32;
        int k0 = (c - 81) * 32;
        if (n < 32) { sg[n] = g2[k0 + n]; sb[n] = bb2[k0 + n]; }
        __syncthreads();
        float pg = 0, pb = 0;
#pragma unroll 8
        for (int kt = 0; kt < 32; ++kt) {
            float wv = W2[(size_t)(k0 + kt) * D_ + n];
            pg += sg[kt] * wv; pb += sb[kt] * wv;
        }
        atomicAdd(&tabF[TB_W2G * 256 + n], pg);
        atomicAdd(&tabF[TB_B2  * 256 + n], pb);
    } else if (c < 153) {
        // fragment-order weight writer: flat[((cg*8+kk)*64+lane)*8+e]
        int fb = c - 89;                 // 0..63
        const float* W = (fb < 32) ? W1 : W2;
        const float* g = (fb < 32) ? g1 : g2;
        u16* dst = (fb < 32) ? wdt : w2t;
        int cid = (fb & 31) * 256 + n;
        int l = cid & 63;
        int col = ((cid >> 9) << 4) + (l & 15);
        int kb = (((cid >> 6) & 7) << 5) + ((l >> 4) << 3);
        bf16x8 v;
#pragma unroll
        for (int e = 0; e < 8; ++e)
            v[e] = (short)f2bf(g[kb + e] * W[(size_t)(kb + e) * D_ + col]);
        *(bf16x8*)&dst[(size_t)cid * 8] = v;
    } else {
        float* sv = (float*)sh;
        float* sqv = sv + 176;
        int sid = sysid[0];
        if (n < 160) {
            int s5 = n >> 5, s = n & 31;
            float v = ce[ctm[sid * 20 + s5 + (s >> 3)] * CED_ + (s & 7)];
            sv[n] = v; sqv[n] = v * v;
        } else if (n < 176) {
            float v = se[sid * SED_ + (n - 160)];
            sv[n] = v; sqv[n] = v * v;
        }
        __syncthreads();
        if (n < 5) {
            float a = 0, bq = 0;
            for (int j2 = 0; j2 < 32; ++j2) { a += sv[n * 32 + j2]; bq += sqv[n * 32 + j2]; }
            scal[n] = a; scal[5 + n] = bq;
        }
        if (n == 10) {
            float a = 0, bq = 0;
            for (int j2 = 0; j2 < 16; ++j2) { a += sv[160 + j2]; bq += sqv[160 + j2]; }
            scal[10] = a; scal[11] = bq;
        }
        if (n >= 12 && n < 16) scal[n] = 0.f;
    }
}

// ================================================================= main fused
// M=16 rows/block, 512 threads (8 waves, each owns 32 cols), grid 1024.
// A-fragments gathered DIRECTLY from x (global) — no LDS staging for GEMM1,
// LN1 stats fully in-wave. ONE barrier total (H + LN2-partials handoff).
__global__ __launch_bounds__(512, 4) void k_main(
    const float* __restrict__ x, const float* __restrict__ fs,
    const int* __restrict__ sLp, const int* __restrict__ sCp,
    const u16* __restrict__ wdt, const u16* __restrict__ w2t,
    const float* __restrict__ tabF, const float* __restrict__ scal,
    const float* __restrict__ b1, const float* __restrict__ b2,
    float* __restrict__ out)
{
    __shared__ __attribute__((aligned(16))) u16 Hs[16 * 264];   // 8448 B, 2-way-max banks
    __shared__ __attribute__((aligned(16))) float ps1[16 * 8], ps2[16 * 8];

    int t = threadIdx.x;
    int tile = ((blockIdx.x & 7) << 7) + (blockIdx.x >> 3);   // 8x128 XCD-bijective
    int r0 = tile * 16;
    int b = tile >> 5;                                        // 32 tiles / batch
    int w = t >> 6, lane = t & 63, l15 = lane & 15, hi = lane >> 4;
    int col0 = w * 32;

    float fsinv = 1.0f / fs[b];
    int sL = sLp[r0 + l15];                                   // own row = l15
    int sC = sCp[r0 + l15];

    // ---- issue ALL independent loads up front ------------------------------
    // GEMM1 B fragments (fragment-order, 1KB/wave coalesced)
    bf16x8 bA[8], bB[8];
    {
        const u16* p0 = &wdt[(size_t)(((2 * w) * 8) * 64 + lane) * 8];
        const u16* p1 = &wdt[(size_t)(((2 * w + 1) * 8) * 64 + lane) * 8];
#pragma unroll
        for (int kk = 0; kk < 8; ++kk) {
            bA[kk] = *(const bf16x8*)(p0 + (size_t)kk * 512);
            bB[kk] = *(const bf16x8*)(p1 + (size_t)kk * 512);
        }
    }
    // epilogue tables (per-lane 2 columns), incl. 5 ch values per fn
    float vwts[2], viwt[2], vsys[2], vgw1[2], vbwb[2], vW2G[2], vB2v[2];
    float ch[2][5];
#pragma unroll
    for (int fn = 0; fn < 2; ++fn) {
        int colf = col0 + fn * 16 + l15;
        vwts[fn] = tabF[TB_WTS * 256 + colf];
        viwt[fn] = tabF[TB_IWT * 256 + colf];
        vsys[fn] = tabF[TB_SYS * 256 + colf];
        vgw1[fn] = tabF[TB_GW1 * 256 + colf];
        vbwb[fn] = tabF[TB_BWB * 256 + colf] + b1[colf];
        vW2G[fn] = tabF[TB_W2G * 256 + colf];
        vB2v[fn] = tabF[TB_B2  * 256 + colf] + b2[colf];
#pragma unroll
        for (int s5 = 0; s5 < 5; ++s5)
            ch[fn][s5] = tabF[(TB_CH0 + s5) * 256 + colf];
    }
    float sc_s = scal[sC], sc_q = scal[5 + sC];
    float sc_sys = scal[10], sc_sysq = scal[11];

    // ---- A-fragment direct gather + LN1 sums (row = l15) -------------------
    bf16x8 a[8];
    float s = 0.f, sq = 0.f;
    {
        const float* xb = x + ((size_t)b << 16);
#pragma unroll
        for (int kk = 0; kk < 8; ++kk) {
            int i = kk * 8 + hi * 2;
            const float* px = xb + (size_t)(sL + i) * 8 + sC;
            f32x4 v0, v1;
            __builtin_memcpy(&v0, px, 16);
            __builtin_memcpy(&v1, px + 8, 16);
            s += v0[0] + v0[1] + v0[2] + v0[3] + v1[0] + v1[1] + v1[2] + v1[3];
            sq += v0[0]*v0[0] + v0[1]*v0[1] + v0[2]*v0[2] + v0[3]*v0[3]
                + v1[0]*v1[0] + v1[1]*v1[1] + v1[2]*v1[2] + v1[3]*v1[3];
            bf16x8 av;
            av[0] = (short)f2bf(v0[0]); av[1] = (short)f2bf(v0[1]);
            av[2] = (short)f2bf(v0[2]); av[3] = (short)f2bf(v0[3]);
            av[4] = (short)f2bf(v1[0]); av[5] = (short)f2bf(v1[1]);
            av[6] = (short)f2bf(v1[2]); av[7] = (short)f2bf(v1[3]);
            a[kk] = av;
        }
    }
    // full row-sum for row l15: reduce over hi (lanes l15, l15+16, +32, +48)
    s  += __shfl_xor(s, 16);  s  += __shfl_xor(s, 32);
    sq += __shfl_xor(sq, 16); sq += __shfl_xor(sq, 32);
    float mu, rs, sLf = (float)sL;
    {
        float Ss = s + 4.f * fsinv * (64.f * sLf + 2016.f) + 64.f * sc_s + sc_sys;
        float Sq = sq + 4.f * fsinv * fsinv * (64.f * sLf * sLf + 4032.f * sLf + 85344.f)
                 + 64.f * sc_q + sc_sysq;
        mu = Ss * (1.f / (float)INDIM);
        float var = Sq * (1.f / (float)INDIM) - mu * mu;
        rs = rsqrtf(var + 1e-5f);
    }

    // ---- GEMM1 (K=256): pure register MFMA ---------------------------------
    f32x4 acc0 = (f32x4){0.f,0.f,0.f,0.f}, acc1 = (f32x4){0.f,0.f,0.f,0.f};
#pragma unroll
    for (int kk = 0; kk < 8; ++kk) {
        acc0 = __builtin_amdgcn_mfma_f32_16x16x32_bf16(a[kk], bA[kk], acc0, 0, 0, 0);
        acc1 = __builtin_amdgcn_mfma_f32_16x16x32_bf16(a[kk], bB[kk], acc1, 0, 0, 0);
    }

    // GEMM2 B preload (lands under epilogue-1)
    {
        const u16* p0 = &w2t[(size_t)(((2 * w) * 8) * 64 + lane) * 8];
        const u16* p1 = &w2t[(size_t)(((2 * w + 1) * 8) * 64 + lane) * 8];
#pragma unroll
        for (int kk = 0; kk < 8; ++kk) {
            bA[kk] = *(const bf16x8*)(p0 + (size_t)kk * 512);
            bB[kk] = *(const bf16x8*)(p1 + (size_t)kk * 512);
        }
    }

    // ---- epilogue1: LN1-fold + SiLU -> Hs, LN2 partials (in-wave) ----------
#pragma unroll
    for (int j = 0; j < 4; ++j) {
        int rr = hi * 4 + j;                       // output row this lane owns
        float muj = __shfl(mu, rr);
        float rsj = __shfl(rs, rr);
        float sLj = __shfl(sLf, rr);
        int   sCj = __shfl(sC, rr);
        float p_s = 0.f, p_q = 0.f;
#pragma unroll
        for (int fn = 0; fn < 2; ++fn) {
            float chv = (sCj < 2) ? (sCj == 0 ? ch[fn][0] : ch[fn][1])
                                  : (sCj == 2 ? ch[fn][2] : (sCj == 3 ? ch[fn][3] : ch[fn][4]));
            float av = (fn == 0) ? acc0[j] : acc1[j];
            float fw = av + fsinv * (sLj * vwts[fn] + viwt[fn]) + chv + vsys[fn];
            float o1 = rsj * (fw - muj * vgw1[fn]) + vbwb[fn];
            float h = o1 / (1.f + __expf(-o1));    // SiLU
            p_s += h; p_q += h * h;
            Hs[rr * 264 + col0 + fn * 16 + l15] = f2bf(h);
        }
        // reduce over the wave's 32 cols (sum over l15 within hi-group)
        p_s += __shfl_xor(p_s, 1); p_s += __shfl_xor(p_s, 2);
        p_s += __shfl_xor(p_s, 4); p_s += __shfl_xor(p_s, 8);
        p_q += __shfl_xor(p_q, 1); p_q += __shfl_xor(p_q, 2);
        p_q += __shfl_xor(p_q, 4); p_q += __shfl_xor(p_q, 8);
        if (l15 == 0) { ps1[rr * 8 + w] = p_s; ps2[rr * 8 + w] = p_q; }
    }
    __syncthreads();                               // THE barrier

    // ---- GEMM2 (K=256): A from Hs (LDS), B in regs; stats2 interleaved -----
    f32x4 acc2a = (f32x4){0.f,0.f,0.f,0.f}, acc2b = (f32x4){0.f,0.f,0.f,0.f};
#pragma unroll
    for (int kk = 0; kk < 8; ++kk) {
        bf16x8 a2 = *(const bf16x8*)&Hs[l15 * 264 + kk * 32 + hi * 8];
        acc2a = __builtin_amdgcn_mfma_f32_16x16x32_bf16(a2, bA[kk], acc2a, 0, 0, 0);
        acc2b = __builtin_amdgcn_mfma_f32_16x16x32_bf16(a2, bB[kk], acc2b, 0, 0, 0);
    }
    float mu2[4], rs2[4];
#pragma unroll
    for (int j = 0; j < 4; ++j) {
        int rr = hi * 4 + j;
        f32x4 q0 = *(f32x4*)&ps1[rr * 8], q1 = *(f32x4*)&ps1[rr * 8 + 4];
        f32x4 q2 = *(f32x4*)&ps2[rr * 8], q3 = *(f32x4*)&ps2[rr * 8 + 4];
        float ts = q0[0]+q0[1]+q0[2]+q0[3] + q1[0]+q1[1]+q1[2]+q1[3];
        float tq = q2[0]+q2[1]+q2[2]+q2[3] + q3[0]+q3[1]+q3[2]+q3[3];
        mu2[j] = ts * (1.f / 256.f);
        float var2 = tq * (1.f / 256.f) - mu2[j] * mu2[j];
        rs2[j] = rsqrtf(var2 + 1e-5f);
    }

    // ---- epilogue2: LN2-fold -> out ----------------------------------------
#pragma unroll
    for (int j = 0; j < 4; ++j) {
        int rr = hi * 4 + j;
        float o0 = rs2[j] * (acc2a[j] - mu2[j] * vW2G[0]) + vB2v[0];
        float o1 = rs2[j] * (acc2b[j] - mu2[j] * vW2G[1]) + vB2v[1];
        out[(size_t)(r0 + rr) * 256 + col0 + l15]      = o0;
        out[(size_t)(r0 + rr) * 256 + col0 + 16 + l15] = o1;
    }
}

// ================================================================= launch
extern "C" void kernel_launch(void* const* d_in, const int* in_sizes, int n_in,
                              void* d_out, int out_size, void* d_ws, size_t ws_size,
                              hipStream_t stream) {
    const float* x   = (const float*)d_in[0];
    const float* fs  = (const float*)d_in[1];
    const float* ce  = (const float*)d_in[2];
    const float* se  = (const float*)d_in[3];
    const float* g1  = (const float*)d_in[4];
    const float* bb1 = (const float*)d_in[5];
    const float* W1  = (const float*)d_in[6];
    const float* b1  = (const float*)d_in[7];
    const float* g2  = (const float*)d_in[8];
    const float* bb2 = (const float*)d_in[9];
    const float* W2  = (const float*)d_in[10];
    const float* b2  = (const float*)d_in[11];
    const int* sL    = (const int*)d_in[12];
    const int* sC    = (const int*)d_in[13];
    const int* ctm   = (const int*)d_in[14];
    const int* sysid = (const int*)d_in[15];
    float* out = (float*)d_out;

    char* ws = (char*)d_ws;
    u16*   wdt  = (u16*)(ws + 0);          // 131072 B (fragment order)
    u16*   w2t  = (u16*)(ws + 131072);     // 131072 B (fragment order)
    float* tabF = (float*)(ws + 262144);   // 12288 B
    float* scal = (float*)(ws + 274432);   // 64 B

    k_zero<<<dim3(12), dim3(256), 0, stream>>>(tabF);
    k_prep<<<dim3(154), dim3(256), 0, stream>>>(
        W1, W2, g1, bb1, g2, bb2, ce, se, ctm, sysid, wdt, w2t, tabF, scal);
    k_main<<<dim3(NROWS / 16), dim3(512), 0, stream>>>(
        x, fs, sL, sC, wdt, w2t, tabF, scal, b1, b2, out);
}

// Round 13
// 53.536 us; speedup vs baseline: 1.1246x; 1.1246x over previous
//
#include <hip/hip_runtime.h>
#include <hip/hip_bf16.h>

typedef short bf16x8 __attribute__((ext_vector_type(8)));
typedef float f32x4 __attribute__((ext_vector_type(4)));
typedef unsigned short u16;

#define B_    32
#define L_    8192
#define C_    8
#define P_    512
#define D_    256
#define SED_  16
#define CED_  8
#define INDIM 2576
#define NROWS (B_ * P_)

#define TB_WTS 0
#define TB_IWT 1
#define TB_SYS 2
#define TB_GW1 3
#define TB_BWB 4
#define TB_CH0 5
#define TB_W2G 10
#define TB_B2  11

__device__ __forceinline__ u16 f2bf(float f) {
    __hip_bfloat16 h = __float2bfloat16(f);
    return *reinterpret_cast<u16*>(&h);
}

// ================================================================= zero tabF + st2
__global__ __launch_bounds__(256) void k_zero(float* __restrict__ z) {
    z[blockIdx.x * 256 + threadIdx.x] = 0.f;
}

// ================================================================= prep (r9/r10 version — verified)
__global__ __launch_bounds__(256) void k_prep(
    const float* __restrict__ W1, const float* __restrict__ W2,
    const float* __restrict__ g1, const float* __restrict__ bb1,
    const float* __restrict__ g2, const float* __restrict__ bb2,
    const float* __restrict__ ce, const float* __restrict__ se,
    const int* __restrict__ ctm, const int* __restrict__ sysid,
    u16* __restrict__ wdt, u16* __restrict__ w2t,
    float* __restrict__ tabF, float* __restrict__ scal)
{
    __shared__ __attribute__((aligned(16))) char sh[8320];
    int c = blockIdx.x, n = threadIdx.x;

    if (c < 81) {
        float* sg = (float*)sh;
        float* sb = sg + 32;
        float* st = sb + 32;
        float (*cs5)[32] = (float(*)[32])(st + 32);
        int sid = sysid[0];
        int k0 = c * 32;
        int kend = INDIM - k0; if (kend > 32) kend = 32;
        int type = (k0 < 256) ? 0 : (k0 < 512) ? 1 : (k0 < 2560) ? 2 : 3;
        if (n < kend) {
            int k = k0 + n;
            sg[n] = g1[k]; sb[n] = bb1[k];
            float xv = 0.f;
            if (type == 1) xv = (float)((k - 256) >> 2);
            if (type == 3) xv = se[sid * SED_ + (k - 2560)];
            st[n] = xv;
        }
        if (type == 2 && n < 160) {
            int s = n >> 5, kt = n & 31, k = k0 + kt;
            cs5[s][kt] = ce[ctm[sid * 20 + s + ((k >> 3) & 3)] * CED_ + (k & 7)];
        }
        __syncthreads();
        float pg = 0, pb = 0, ai = 0, as_ = 0;
        float a5 = 0, a6 = 0, a7 = 0, a8 = 0, a9 = 0;
#pragma unroll 8
        for (int kt = 0; kt < kend; ++kt) {
            float wv = W1[(size_t)(k0 + kt) * D_ + n];
            float gw = sg[kt] * wv;
            pg += gw; pb += sb[kt] * wv;
            if (type == 1) ai += st[kt] * gw;
            if (type == 2) {
                a5 += cs5[0][kt] * gw; a6 += cs5[1][kt] * gw; a7 += cs5[2][kt] * gw;
                a8 += cs5[3][kt] * gw; a9 += cs5[4][kt] * gw;
            }
            if (type == 3) as_ += st[kt] * gw;
        }
        atomicAdd(&tabF[TB_GW1 * 256 + n], pg);
        atomicAdd(&tabF[TB_BWB * 256 + n], pb);
        if (type == 1) {
            atomicAdd(&tabF[TB_WTS * 256 + n], pg);
            atomicAdd(&tabF[TB_IWT * 256 + n], ai);
        }
        if (type == 2) {
            atomicAdd(&tabF[(TB_CH0 + 0) * 256 + n], a5);
            atomicAdd(&tabF[(TB_CH0 + 1) * 256 + n], a6);
            atomicAdd(&tabF[(TB_CH0 + 2) * 256 + n], a7);
            atomicAdd(&tabF[(TB_CH0 + 3) * 256 + n], a8);
            atomicAdd(&tabF[(TB_CH0 + 4) * 256 + n], a9);
        }
        if (type == 3) atomicAdd(&tabF[TB_SYS * 256 + n], as_);
    } else if (c < 89) {
        float* sg = (float*)sh;
        float* sb = sg + 32;
        int k0 = (c - 81) * 32;
        if (n < 32) { sg[n] = g2[k0 + n]; sb[n] = bb2[k0 + n]; }
        __syncthreads();
        float pg = 0, pb = 0;
#pragma unroll 8
        for (int kt = 0; kt < 32; ++kt) {
            float wv = W2[(size_t)(k0 + kt) * D_ + n];
            pg += sg[kt] * wv; pb += sb[kt] * wv;
        }
        atomicAdd(&tabF[TB_W2G * 256 + n], pg);
        atomicAdd(&tabF[TB_B2  * 256 + n], pb);
    } else if (c < 153) {
        // fragment-order weight writer: flat[((cg*8+kk)*64+lane)*8+e]
        int fb = c - 89;
        const float* W = (fb < 32) ? W1 : W2;
        const float* g = (fb < 32) ? g1 : g2;
        u16* dst = (fb < 32) ? wdt : w2t;
        int cid = (fb & 31) * 256 + n;
        int l = cid & 63;
        int col = ((cid >> 9) << 4) + (l & 15);
        int kb = (((cid >> 6) & 7) << 5) + ((l >> 4) << 3);
        bf16x8 v;
#pragma unroll
        for (int e = 0; e < 8; ++e)
            v[e] = (short)f2bf(g[kb + e] * W[(size_t)(kb + e) * D_ + col]);
        *(bf16x8*)&dst[(size_t)cid * 8] = v;
    } else {
        float* sv = (float*)sh;
        float* sqv = sv + 176;
        int sid = sysid[0];
        if (n < 160) {
            int s5 = n >> 5, s = n & 31;
            float v = ce[ctm[sid * 20 + s5 + (s >> 3)] * CED_ + (s & 7)];
            sv[n] = v; sqv[n] = v * v;
        } else if (n < 176) {
            float v = se[sid * SED_ + (n - 160)];
            sv[n] = v; sqv[n] = v * v;
        }
        __syncthreads();
        if (n < 5) {
            float a = 0, bq = 0;
            for (int j2 = 0; j2 < 32; ++j2) { a += sv[n * 32 + j2]; bq += sqv[n * 32 + j2]; }
            scal[n] = a; scal[5 + n] = bq;
        }
        if (n == 10) {
            float a = 0, bq = 0;
            for (int j2 = 0; j2 < 16; ++j2) { a += sv[160 + j2]; bq += sqv[160 + j2]; }
            scal[10] = a; scal[11] = bq;
        }
        if (n >= 12 && n < 16) scal[n] = 0.f;
    }
}

// ================================================================= k_h
// 64x64 output tile, 256 threads = 4 waves (wave w: rows rt*64+w*16..+15,
// all 64 cols). Zero barriers, zero LDS. Gather A direct to fragments,
// LN1 in-wave, GEMM1, fold+SiLU -> H (global bf16), LN2 partials -> atomics.
__global__ __launch_bounds__(256, 3) void k_h(
    const float* __restrict__ x, const float* __restrict__ fs,
    const int* __restrict__ sLp, const int* __restrict__ sCp,
    const u16* __restrict__ wdt, const float* __restrict__ tabF,
    const float* __restrict__ scal, const float* __restrict__ b1,
    u16* __restrict__ Hg, float* __restrict__ st2s, float* __restrict__ st2q)
{
    int t = threadIdx.x, bid = blockIdx.x;
    int rt = bid & 255, ct = bid >> 8;
    int w = t >> 6, lane = t & 63, l15 = lane & 15, hi = lane >> 4;
    int rbase = rt * 64 + w * 16;
    int col00 = ct * 64;
    int b = rbase >> 9;
    float fsinv = 1.0f / fs[b];

    int sL = sLp[rbase + l15], sC = sCp[rbase + l15];

    // ---- direct-fragment gather + LN1 sums (row = l15; r11-verified map)
    bf16x8 a[8];
    float s = 0.f, sq = 0.f;
    {
        const float* xb = x + ((size_t)b << 16);
#pragma unroll
        for (int kk = 0; kk < 8; ++kk) {
            int i = kk * 8 + hi * 2;
            const float* px = xb + (size_t)(sL + i) * 8 + sC;
            f32x4 v0, v1;
            __builtin_memcpy(&v0, px, 16);
            __builtin_memcpy(&v1, px + 8, 16);
            s += v0[0] + v0[1] + v0[2] + v0[3] + v1[0] + v1[1] + v1[2] + v1[3];
            sq += v0[0]*v0[0] + v0[1]*v0[1] + v0[2]*v0[2] + v0[3]*v0[3]
                + v1[0]*v1[0] + v1[1]*v1[1] + v1[2]*v1[2] + v1[3]*v1[3];
            bf16x8 av;
            av[0] = (short)f2bf(v0[0]); av[1] = (short)f2bf(v0[1]);
            av[2] = (short)f2bf(v0[2]); av[3] = (short)f2bf(v0[3]);
            av[4] = (short)f2bf(v1[0]); av[5] = (short)f2bf(v1[1]);
            av[6] = (short)f2bf(v1[2]); av[7] = (short)f2bf(v1[3]);
            a[kk] = av;
        }
    }
    s  += __shfl_xor(s, 16);  s  += __shfl_xor(s, 32);
    sq += __shfl_xor(sq, 16); sq += __shfl_xor(sq, 32);
    float sLf = (float)sL, mu, rs;
    {
        float Ss = s + 4.f * fsinv * (64.f * sLf + 2016.f) + 64.f * scal[sC] + scal[10];
        float Sq = sq + 4.f * fsinv * fsinv * (64.f * sLf * sLf + 4032.f * sLf + 85344.f)
                 + 64.f * scal[5 + sC] + scal[11];
        mu = Ss * (1.f / (float)INDIM);
        float var = Sq * (1.f / (float)INDIM) - mu * mu;
        rs = rsqrtf(var + 1e-5f);
    }

    // ---- GEMM1 (K=256), B streamed from fragment-order wdt (L2-hot)
    f32x4 acc[4];
#pragma unroll
    for (int cg = 0; cg < 4; ++cg) acc[cg] = (f32x4){0.f, 0.f, 0.f, 0.f};
#pragma unroll
    for (int kk = 0; kk < 8; ++kk) {
        const u16* bp = &wdt[(size_t)((((ct * 4) * 8 + kk) * 64) + lane) * 8];
#pragma unroll
        for (int cg = 0; cg < 4; ++cg) {
            bf16x8 bv = *(const bf16x8*)(bp + (size_t)cg * 4096);
            acc[cg] = __builtin_amdgcn_mfma_f32_16x16x32_bf16(a[kk], bv, acc[cg], 0, 0, 0);
        }
    }

    // ---- per-output-row params (broadcast once)
    float muj[4], rsj[4], sLj[4]; int sCj[4];
#pragma unroll
    for (int j = 0; j < 4; ++j) {
        int rr = hi * 4 + j;
        muj[j] = __shfl(mu, rr);
        rsj[j] = __shfl(rs, rr);
        sLj[j] = __shfl(sLf, rr);
        sCj[j] = __shfl(sC, rr);
    }

    // ---- epilogue: fold + SiLU -> Hg; row-partials for LN2
    float prs[4] = {0.f, 0.f, 0.f, 0.f}, prq[4] = {0.f, 0.f, 0.f, 0.f};
#pragma unroll
    for (int cg = 0; cg < 4; ++cg) {
        int colf = col00 + cg * 16 + l15;
        float vwts = tabF[TB_WTS * 256 + colf];
        float viwt = tabF[TB_IWT * 256 + colf];
        float vsys = tabF[TB_SYS * 256 + colf];
        float vgw1 = tabF[TB_GW1 * 256 + colf];
        float vbwb = tabF[TB_BWB * 256 + colf] + b1[colf];
#pragma unroll
        for (int j = 0; j < 4; ++j) {
            float chv = tabF[(TB_CH0 + sCj[j]) * 256 + colf];
            float fw = acc[cg][j] + fsinv * (sLj[j] * vwts + viwt) + chv + vsys;
            float o1 = rsj[j] * (fw - muj[j] * vgw1) + vbwb;
            float h = o1 / (1.f + __expf(-o1));
            prs[j] += h; prq[j] += h * h;
            Hg[(size_t)(rbase + hi * 4 + j) * 256 + colf] = f2bf(h);
        }
    }
#pragma unroll
    for (int j = 0; j < 4; ++j) {
        float ssum = prs[j], qsum = prq[j];
        ssum += __shfl_xor(ssum, 1); ssum += __shfl_xor(ssum, 2);
        ssum += __shfl_xor(ssum, 4); ssum += __shfl_xor(ssum, 8);
        qsum += __shfl_xor(qsum, 1); qsum += __shfl_xor(qsum, 2);
        qsum += __shfl_xor(qsum, 4); qsum += __shfl_xor(qsum, 8);
        if (l15 == 0) {
            atomicAdd(&st2s[rbase + hi * 4 + j], ssum);
            atomicAdd(&st2q[rbase + hi * 4 + j], qsum);
        }
    }
}

// ================================================================= k_out
// 64x64 tile, 256 threads, zero barriers/LDS. A from Hg (coalesced 16B/lane),
// LN2 finalize from st2, GEMM2, fold -> out.
__global__ __launch_bounds__(256, 4) void k_out(
    const u16* __restrict__ Hg, const u16* __restrict__ w2t,
    const float* __restrict__ tabF, const float* __restrict__ b2,
    const float* __restrict__ st2s, const float* __restrict__ st2q,
    float* __restrict__ out)
{
    int t = threadIdx.x, bid = blockIdx.x;
    int rt = bid & 255, ct = bid >> 8;
    int w = t >> 6, lane = t & 63, l15 = lane & 15, hi = lane >> 4;
    int rbase = rt * 64 + w * 16;
    int col00 = ct * 64;

    bf16x8 a[8];
#pragma unroll
    for (int kk = 0; kk < 8; ++kk)
        a[kk] = *(const bf16x8*)&Hg[(size_t)(rbase + l15) * 256 + kk * 32 + hi * 8];

    float mu2[4], rs2[4];
#pragma unroll
    for (int j = 0; j < 4; ++j) {
        int rr = rbase + hi * 4 + j;
        float ts = st2s[rr], tq = st2q[rr];
        mu2[j] = ts * (1.f / 256.f);
        float var2 = tq * (1.f / 256.f) - mu2[j] * mu2[j];
        rs2[j] = rsqrtf(var2 + 1e-5f);
    }

    f32x4 acc[4];
#pragma unroll
    for (int cg = 0; cg < 4; ++cg) acc[cg] = (f32x4){0.f, 0.f, 0.f, 0.f};
#pragma unroll
    for (int kk = 0; kk < 8; ++kk) {
        const u16* bp = &w2t[(size_t)((((ct * 4) * 8 + kk) * 64) + lane) * 8];
#pragma unroll
        for (int cg = 0; cg < 4; ++cg) {
            bf16x8 bv = *(const bf16x8*)(bp + (size_t)cg * 4096);
            acc[cg] = __builtin_amdgcn_mfma_f32_16x16x32_bf16(a[kk], bv, acc[cg], 0, 0, 0);
        }
    }

#pragma unroll
    for (int cg = 0; cg < 4; ++cg) {
        int colf = col00 + cg * 16 + l15;
        float vW2G = tabF[TB_W2G * 256 + colf];
        float vB2  = tabF[TB_B2  * 256 + colf] + b2[colf];
#pragma unroll
        for (int j = 0; j < 4; ++j) {
            float o = rs2[j] * (acc[cg][j] - mu2[j] * vW2G) + vB2;
            out[(size_t)(rbase + hi * 4 + j) * 256 + colf] = o;
        }
    }
}

// ================================================================= launch
extern "C" void kernel_launch(void* const* d_in, const int* in_sizes, int n_in,
                              void* d_out, int out_size, void* d_ws, size_t ws_size,
                              hipStream_t stream) {
    const float* x   = (const float*)d_in[0];
    const float* fs  = (const float*)d_in[1];
    const float* ce  = (const float*)d_in[2];
    const float* se  = (const float*)d_in[3];
    const float* g1  = (const float*)d_in[4];
    const float* bb1 = (const float*)d_in[5];
    const float* W1  = (const float*)d_in[6];
    const float* b1  = (const float*)d_in[7];
    const float* g2  = (const float*)d_in[8];
    const float* bb2 = (const float*)d_in[9];
    const float* W2  = (const float*)d_in[10];
    const float* b2  = (const float*)d_in[11];
    const int* sL    = (const int*)d_in[12];
    const int* sC    = (const int*)d_in[13];
    const int* ctm   = (const int*)d_in[14];
    const int* sysid = (const int*)d_in[15];
    float* out = (float*)d_out;

    char* ws = (char*)d_ws;
    u16*   wdt  = (u16*)(ws + 0);          // 131072 B (fragment order)
    u16*   w2t  = (u16*)(ws + 131072);     // 131072 B (fragment order)
    float* tabF = (float*)(ws + 262144);   // 12288 B (zeroed with st2)
    float* st2s = (float*)(ws + 274432);   // 65536 B (zeroed)
    float* st2q = (float*)(ws + 339968);   // 65536 B (zeroed)
    float* scal = (float*)(ws + 405504);   // 64 B
    u16*   Hg   = (u16*)(ws + 1048576);    // 8388608 B

    k_zero<<<dim3(140), dim3(256), 0, stream>>>((float*)(ws + 262144));
    k_prep<<<dim3(154), dim3(256), 0, stream>>>(
        W1, W2, g1, bb1, g2, bb2, ce, se, ctm, sysid, wdt, w2t, tabF, scal);
    k_h<<<dim3(1024), dim3(256), 0, stream>>>(
        x, fs, sL, sC, wdt, tabF, scal, b1, Hg, st2s, st2q);
    k_out<<<dim3(1024), dim3(256), 0, stream>>>(
        Hg, w2t, tabF, b2, st2s, st2q, out);
}

// Round 14
// 42.617 us; speedup vs baseline: 1.4127x; 1.2562x over previous
//
#include <hip/hip_runtime.h>
#include <hip/hip_bf16.h>

typedef short bf16x8 __attribute__((ext_vector_type(8)));
typedef float f32x4 __attribute__((ext_vector_type(4)));
typedef unsigned short u16;

#define B_    32
#define L_    8192
#define C_    8
#define P_    512
#define D_    256
#define SED_  16
#define CED_  8
#define INDIM 2576
#define NROWS (B_ * P_)

#define TB_WTS 0
#define TB_IWT 1
#define TB_SYS 2
#define TB_GW1 3
#define TB_BWB 4
#define TB_CH0 5
#define TB_W2G 10
#define TB_B2  11

__device__ __forceinline__ u16 f2bf(float f) {
    __hip_bfloat16 h = __float2bfloat16(f);
    return *reinterpret_cast<u16*>(&h);
}

// ================================================================= prep (r9/r10 version — verified)
__global__ __launch_bounds__(256) void k_prep(
    const float* __restrict__ W1, const float* __restrict__ W2,
    const float* __restrict__ g1, const float* __restrict__ bb1,
    const float* __restrict__ g2, const float* __restrict__ bb2,
    const float* __restrict__ ce, const float* __restrict__ se,
    const int* __restrict__ ctm, const int* __restrict__ sysid,
    u16* __restrict__ wdt, u16* __restrict__ w2t,
    float* __restrict__ tabF, float* __restrict__ scal)
{
    __shared__ __attribute__((aligned(16))) char sh[8320];
    int c = blockIdx.x, n = threadIdx.x;

    if (c < 81) {
        float* sg = (float*)sh;
        float* sb = sg + 32;
        float* st = sb + 32;
        float (*cs5)[32] = (float(*)[32])(st + 32);
        int sid = sysid[0];
        int k0 = c * 32;
        int kend = INDIM - k0; if (kend > 32) kend = 32;
        int type = (k0 < 256) ? 0 : (k0 < 512) ? 1 : (k0 < 2560) ? 2 : 3;
        if (n < kend) {
            int k = k0 + n;
            sg[n] = g1[k]; sb[n] = bb1[k];
            float xv = 0.f;
            if (type == 1) xv = (float)((k - 256) >> 2);
            if (type == 3) xv = se[sid * SED_ + (k - 2560)];
            st[n] = xv;
        }
        if (type == 2 && n < 160) {
            int s = n >> 5, kt = n & 31, k = k0 + kt;
            cs5[s][kt] = ce[ctm[sid * 20 + s + ((k >> 3) & 3)] * CED_ + (k & 7)];
        }
        __syncthreads();
        float pg = 0, pb = 0, ai = 0, as_ = 0;
        float a5 = 0, a6 = 0, a7 = 0, a8 = 0, a9 = 0;
#pragma unroll 8
        for (int kt = 0; kt < kend; ++kt) {
            float wv = W1[(size_t)(k0 + kt) * D_ + n];
            float gw = sg[kt] * wv;
            pg += gw; pb += sb[kt] * wv;
            if (type == 1) ai += st[kt] * gw;
            if (type == 2) {
                a5 += cs5[0][kt] * gw; a6 += cs5[1][kt] * gw; a7 += cs5[2][kt] * gw;
                a8 += cs5[3][kt] * gw; a9 += cs5[4][kt] * gw;
            }
            if (type == 3) as_ += st[kt] * gw;
        }
        atomicAdd(&tabF[TB_GW1 * 256 + n], pg);
        atomicAdd(&tabF[TB_BWB * 256 + n], pb);
        if (type == 1) {
            atomicAdd(&tabF[TB_WTS * 256 + n], pg);
            atomicAdd(&tabF[TB_IWT * 256 + n], ai);
        }
        if (type == 2) {
            atomicAdd(&tabF[(TB_CH0 + 0) * 256 + n], a5);
            atomicAdd(&tabF[(TB_CH0 + 1) * 256 + n], a6);
            atomicAdd(&tabF[(TB_CH0 + 2) * 256 + n], a7);
            atomicAdd(&tabF[(TB_CH0 + 3) * 256 + n], a8);
            atomicAdd(&tabF[(TB_CH0 + 4) * 256 + n], a9);
        }
        if (type == 3) atomicAdd(&tabF[TB_SYS * 256 + n], as_);
    } else if (c < 89) {
        float* sg = (float*)sh;
        float* sb = sg + 32;
        int k0 = (c - 81) * 32;
        if (n < 32) { sg[n] = g2[k0 + n]; sb[n] = bb2[k0 + n]; }
        __syncthreads();
        float pg = 0, pb = 0;
#pragma unroll 8
        for (int kt = 0; kt < 32; ++kt) {
            float wv = W2[(size_t)(k0 + kt) * D_ + n];
            pg += sg[kt] * wv; pb += sb[kt] * wv;
        }
        atomicAdd(&tabF[TB_W2G * 256 + n], pg);
        atomicAdd(&tabF[TB_B2  * 256 + n], pb);
    } else if (c < 153) {
        // fragment-order weight writer: flat[((cg*8+kk)*64+lane)*8+e]
        int fb = c - 89;
        const float* W = (fb < 32) ? W1 : W2;
        const float* g = (fb < 32) ? g1 : g2;
        u16* dst = (fb < 32) ? wdt : w2t;
        int cid = (fb & 31) * 256 + n;
        int l = cid & 63;
        int col = ((cid >> 9) << 4) + (l & 15);
        int kb = (((cid >> 6) & 7) << 5) + ((l >> 4) << 3);
        bf16x8 v;
#pragma unroll
        for (int e = 0; e < 8; ++e)
            v[e] = (short)f2bf(g[kb + e] * W[(size_t)(kb + e) * D_ + col]);
        *(bf16x8*)&dst[(size_t)cid * 8] = v;
    } else {
        float* sv = (float*)sh;
        float* sqv = sv + 176;
        int sid = sysid[0];
        if (n < 160) {
            int s5 = n >> 5, s = n & 31;
            float v = ce[ctm[sid * 20 + s5 + (s >> 3)] * CED_ + (s & 7)];
            sv[n] = v; sqv[n] = v * v;
        } else if (n < 176) {
            float v = se[sid * SED_ + (n - 160)];
            sv[n] = v; sqv[n] = v * v;
        }
        __syncthreads();
        if (n < 5) {
            float a = 0, bq = 0;
            for (int j2 = 0; j2 < 32; ++j2) { a += sv[n * 32 + j2]; bq += sqv[n * 32 + j2]; }
            scal[n] = a; scal[5 + n] = bq;
        }
        if (n == 10) {
            float a = 0, bq = 0;
            for (int j2 = 0; j2 < 16; ++j2) { a += sv[160 + j2]; bq += sqv[160 + j2]; }
            scal[10] = a; scal[11] = bq;
        }
        if (n >= 12 && n < 16) scal[n] = 0.f;
    }
}

// ================================================================= main fused
// r10 structure (best measured): M=32, 512 threads, grid 512, 2 blocks/CU,
// fragment-order B preloaded to regs. NEW: all epilogue tables preloaded to
// registers BEFORE barrier B1 (no L2 reads after GEMM phases).
__global__ __launch_bounds__(512, 4) void k_main(
    const float* __restrict__ x, const float* __restrict__ fs,
    const int* __restrict__ sLp, const int* __restrict__ sCp,
    const u16* __restrict__ wdt, const u16* __restrict__ w2t,
    const float* __restrict__ tabF, const float* __restrict__ scal,
    const float* __restrict__ b1, const float* __restrict__ b2,
    float* __restrict__ out)
{
    __shared__ __attribute__((aligned(16))) u16 As[8 * 32 * 40];
    __shared__ __attribute__((aligned(16))) u16 Hs[8 * 32 * 40];
    __shared__ __attribute__((aligned(16))) float ps1[32 * 8], ps2[32 * 8];
    __shared__ float rmu[32], rrs[32], rsl[32];
    __shared__ int   rsc[32];
    __shared__ float rmu2[32], rrs2[32];

    int t = threadIdx.x;
    int tile = ((blockIdx.x & 7) << 6) + (blockIdx.x >> 3);   // XCD-bijective
    int r0 = tile * 32;
    int b = r0 >> 9;
    float fsinv = 1.0f / fs[b];

    int row = t >> 4, u = t & 15;
    int w = t >> 6, lane = t & 63, l15 = lane & 15, hi = lane >> 4;
    int col0 = w * 32;

    int r = r0 + row;
    int sL = sLp[r], sC = sCp[r];

    // ---- GEMM1 B preload (fragment-order, 1 KB/wave coalesced) -------------
    bf16x8 bA[8], bB[8];
    {
        const u16* p0 = &wdt[(size_t)(((2 * w) * 8) * 64 + lane) * 8];
        const u16* p1 = &wdt[(size_t)(((2 * w + 1) * 8) * 64 + lane) * 8];
#pragma unroll
        for (int kk = 0; kk < 8; ++kk) {
            bA[kk] = *(const bf16x8*)(p0 + (size_t)kk * 512);
            bB[kk] = *(const bf16x8*)(p1 + (size_t)kk * 512);
        }
    }

    // ---- NEW: preload ALL epilogue tables to registers (independent loads,
    //      issued under gather latency; nothing L2-bound after GEMM phases)
    float vwts[2], viwt[2], vsys[2], vgw1[2], vbwb[2], vW2G[2], vB2v[2];
    float ch0[2], ch1[2], ch2[2], ch3[2], ch4[2];
#pragma unroll
    for (int fn = 0; fn < 2; ++fn) {
        int colf = col0 + fn * 16 + l15;
        vwts[fn] = tabF[TB_WTS * 256 + colf];
        viwt[fn] = tabF[TB_IWT * 256 + colf];
        vsys[fn] = tabF[TB_SYS * 256 + colf];
        vgw1[fn] = tabF[TB_GW1 * 256 + colf];
        vbwb[fn] = tabF[TB_BWB * 256 + colf] + b1[colf];
        vW2G[fn] = tabF[TB_W2G * 256 + colf];
        vB2v[fn] = tabF[TB_B2  * 256 + colf] + b2[colf];
        ch0[fn] = tabF[(TB_CH0 + 0) * 256 + colf];
        ch1[fn] = tabF[(TB_CH0 + 1) * 256 + colf];
        ch2[fn] = tabF[(TB_CH0 + 2) * 256 + colf];
        ch3[fn] = tabF[(TB_CH0 + 3) * 256 + colf];
        ch4[fn] = tabF[(TB_CH0 + 4) * 256 + colf];
    }
    float sc_s = scal[sC], sc_q = scal[5 + sC];
    float sc_y = scal[10], sc_z = scal[11];

    // ---- gather + LN1 stats (16 threads/row, shfl reduce) ------------------
    {
        const float* xb = x + ((size_t)b << 16);
        float s = 0.f, sq = 0.f;
#pragma unroll
        for (int i2 = 0; i2 < 4; ++i2) {
            int i = i2 * 16 + u;
            const float* px = xb + (size_t)(sL + i) * 8 + sC;
            f32x4 v;
            __builtin_memcpy(&v, px, 16);
            s += v[0] + v[1] + v[2] + v[3];
            sq += v[0] * v[0] + v[1] * v[1] + v[2] * v[2] + v[3] * v[3];
            *(ushort4*)&As[(i2 * 2 + (u >> 3)) * 1280 + row * 40 + (u & 7) * 4] =
                make_ushort4(f2bf(v[0]), f2bf(v[1]), f2bf(v[2]), f2bf(v[3]));
        }
        s += __shfl_xor(s, 1); s += __shfl_xor(s, 2); s += __shfl_xor(s, 4); s += __shfl_xor(s, 8);
        sq += __shfl_xor(sq, 1); sq += __shfl_xor(sq, 2); sq += __shfl_xor(sq, 4); sq += __shfl_xor(sq, 8);
        if (u == 0) {
            float sLf = (float)sL;
            float Ss = s + 4.f * fsinv * (64.f * sLf + 2016.f) + 64.f * sc_s + sc_y;
            float Sq = sq + 4.f * fsinv * fsinv * (64.f * sLf * sLf + 4032.f * sLf + 85344.f)
                     + 64.f * sc_q + sc_z;
            float mu = Ss * (1.f / (float)INDIM);
            float var = Sq * (1.f / (float)INDIM) - mu * mu;
            rmu[row] = mu; rrs[row] = rsqrtf(var + 1e-5f);
            rsl[row] = (float)sL; rsc[row] = sC;
        }
    }
    __syncthreads();                                           // B1

    // ---- GEMM1 (K=256): LDS-A + in-reg B -----------------------------------
    f32x4 acc[2][2];
#pragma unroll
    for (int fm = 0; fm < 2; ++fm)
#pragma unroll
        for (int fn = 0; fn < 2; ++fn) acc[fm][fn] = (f32x4){0.f, 0.f, 0.f, 0.f};
#pragma unroll
    for (int kk = 0; kk < 8; ++kk) {
        bf16x8 a0 = *(const bf16x8*)&As[kk * 1280 + l15 * 40 + hi * 8];
        bf16x8 a1 = *(const bf16x8*)&As[kk * 1280 + (16 + l15) * 40 + hi * 8];
        acc[0][0] = __builtin_amdgcn_mfma_f32_16x16x32_bf16(a0, bA[kk], acc[0][0], 0, 0, 0);
        acc[1][0] = __builtin_amdgcn_mfma_f32_16x16x32_bf16(a1, bA[kk], acc[1][0], 0, 0, 0);
        acc[0][1] = __builtin_amdgcn_mfma_f32_16x16x32_bf16(a0, bB[kk], acc[0][1], 0, 0, 0);
        acc[1][1] = __builtin_amdgcn_mfma_f32_16x16x32_bf16(a1, bB[kk], acc[1][1], 0, 0, 0);
    }

    // ---- GEMM2 B preload (lands under epilogue-1 VALU) ---------------------
    {
        const u16* p0 = &w2t[(size_t)(((2 * w) * 8) * 64 + lane) * 8];
        const u16* p1 = &w2t[(size_t)(((2 * w + 1) * 8) * 64 + lane) * 8];
#pragma unroll
        for (int kk = 0; kk < 8; ++kk) {
            bA[kk] = *(const bf16x8*)(p0 + (size_t)kk * 512);
            bB[kk] = *(const bf16x8*)(p1 + (size_t)kk * 512);
        }
    }

    // ---- epilogue1: LN1-fold + SiLU -> Hs, LN2 partials (all-register) -----
    {
        float p_s[2][4] = {}, p_q[2][4] = {};
#pragma unroll
        for (int fn = 0; fn < 2; ++fn) {
#pragma unroll
            for (int fm = 0; fm < 2; ++fm)
#pragma unroll
                for (int j = 0; j < 4; ++j) {
                    int rr = fm * 16 + hi * 4 + j;
                    int sCc = rsc[rr];
                    float c01 = (sCc == 0) ? ch0[fn] : ch1[fn];
                    float c23 = (sCc == 2) ? ch2[fn] : ch3[fn];
                    float chv = (sCc < 2) ? c01 : ((sCc < 4) ? c23 : ch4[fn]);
                    float fw = acc[fm][fn][j]
                             + fsinv * (rsl[rr] * vwts[fn] + viwt[fn])
                             + chv + vsys[fn];
                    float o1 = rrs[rr] * (fw - rmu[rr] * vgw1[fn]) + vbwb[fn];
                    float h = o1 / (1.f + __expf(-o1));
                    p_s[fm][j] += h; p_q[fm][j] += h * h;
                    Hs[w * 1280 + rr * 40 + fn * 16 + l15] = f2bf(h);
                }
        }
#pragma unroll
        for (int fm = 0; fm < 2; ++fm)
#pragma unroll
            for (int j = 0; j < 4; ++j) {
                float s = p_s[fm][j], q = p_q[fm][j];
                s += __shfl_xor(s, 1); s += __shfl_xor(s, 2); s += __shfl_xor(s, 4); s += __shfl_xor(s, 8);
                q += __shfl_xor(q, 1); q += __shfl_xor(q, 2); q += __shfl_xor(q, 4); q += __shfl_xor(q, 8);
                if (l15 == 0) {
                    int rr = fm * 16 + hi * 4 + j;
                    ps1[rr * 8 + w] = s; ps2[rr * 8 + w] = q;
                }
            }
    }
    __syncthreads();                                           // B2

    // ---- stats2 (t<32) overlapped with GEMM2 -------------------------------
    if (t < 32) {
        f32x4 a = *(f32x4*)&ps1[t * 8], bb = *(f32x4*)&ps1[t * 8 + 4];
        f32x4 cq = *(f32x4*)&ps2[t * 8], dq = *(f32x4*)&ps2[t * 8 + 4];
        float ts = a[0] + a[1] + a[2] + a[3] + bb[0] + bb[1] + bb[2] + bb[3];
        float tq = cq[0] + cq[1] + cq[2] + cq[3] + dq[0] + dq[1] + dq[2] + dq[3];
        float mu2 = ts * (1.f / 256.f);
        float var2 = tq * (1.f / 256.f) - mu2 * mu2;
        rmu2[t] = mu2; rrs2[t] = rsqrtf(var2 + 1e-5f);
    }

    // ---- GEMM2 (K=256): LDS-Hs + in-reg B ----------------------------------
    f32x4 acc2[2][2];
#pragma unroll
    for (int fm = 0; fm < 2; ++fm)
#pragma unroll
        for (int fn = 0; fn < 2; ++fn) acc2[fm][fn] = (f32x4){0.f, 0.f, 0.f, 0.f};
#pragma unroll
    for (int kk = 0; kk < 8; ++kk) {
        bf16x8 a0 = *(const bf16x8*)&Hs[kk * 1280 + l15 * 40 + hi * 8];
        bf16x8 a1 = *(const bf16x8*)&Hs[kk * 1280 + (16 + l15) * 40 + hi * 8];
        acc2[0][0] = __builtin_amdgcn_mfma_f32_16x16x32_bf16(a0, bA[kk], acc2[0][0], 0, 0, 0);
        acc2[1][0] = __builtin_amdgcn_mfma_f32_16x16x32_bf16(a1, bA[kk], acc2[1][0], 0, 0, 0);
        acc2[0][1] = __builtin_amdgcn_mfma_f32_16x16x32_bf16(a0, bB[kk], acc2[0][1], 0, 0, 0);
        acc2[1][1] = __builtin_amdgcn_mfma_f32_16x16x32_bf16(a1, bB[kk], acc2[1][1], 0, 0, 0);
    }
    __syncthreads();                                           // B3

    // ---- epilogue2: LN2-fold -> out (all-register tables) ------------------
#pragma unroll
    for (int fn = 0; fn < 2; ++fn) {
        int colf = col0 + fn * 16 + l15;
#pragma unroll
        for (int fm = 0; fm < 2; ++fm)
#pragma unroll
            for (int j = 0; j < 4; ++j) {
                int rr = fm * 16 + hi * 4 + j;
                float o = rrs2[rr] * (acc2[fm][fn][j] - rmu2[rr] * vW2G[fn]) + vB2v[fn];
                out[(size_t)(r0 + rr) * 256 + colf] = o;
            }
    }
}

// ================================================================= launch
extern "C" void kernel_launch(void* const* d_in, const int* in_sizes, int n_in,
                              void* d_out, int out_size, void* d_ws, size_t ws_size,
                              hipStream_t stream) {
    const float* x   = (const float*)d_in[0];
    const float* fs  = (const float*)d_in[1];
    const float* ce  = (const float*)d_in[2];
    const float* se  = (const float*)d_in[3];
    const float* g1  = (const float*)d_in[4];
    const float* bb1 = (const float*)d_in[5];
    const float* W1  = (const float*)d_in[6];
    const float* b1  = (const float*)d_in[7];
    const float* g2  = (const float*)d_in[8];
    const float* bb2 = (const float*)d_in[9];
    const float* W2  = (const float*)d_in[10];
    const float* b2  = (const float*)d_in[11];
    const int* sL    = (const int*)d_in[12];
    const int* sC    = (const int*)d_in[13];
    const int* ctm   = (const int*)d_in[14];
    const int* sysid = (const int*)d_in[15];
    float* out = (float*)d_out;

    char* ws = (char*)d_ws;
    u16*   wdt  = (u16*)(ws + 0);          // 131072 B (fragment order)
    u16*   w2t  = (u16*)(ws + 131072);     // 131072 B (fragment order)
    float* tabF = (float*)(ws + 262144);   // 12288 B
    float* scal = (float*)(ws + 274432);   // 64 B

    hipMemsetAsync(tabF, 0, 12 * 256 * sizeof(float), stream);
    k_prep<<<dim3(154), dim3(256), 0, stream>>>(
        W1, W2, g1, bb1, g2, bb2, ce, se, ctm, sysid, wdt, w2t, tabF, scal);
    k_main<<<dim3(NROWS / 32), dim3(512), 0, stream>>>(
        x, fs, sL, sC, wdt, w2t, tabF, scal, b1, b2, out);
}